// Round 1
// baseline (138.882 us; speedup 1.0000x reference)
//
#include <hip/hip_runtime.h>

#define NPTS  65536
#define KNB   32
#define KPn   15
#define CIN   64
#define COUT  128
#define MPTS  16            // points per block (MFMA M)
#define THREADS 512         // 8 waves/block
#define WSTRIDE 968         // wl row stride in bf16 elems (960 + 8 pad)
#define BCAP  48            // bucket cap per point
#define RCAP  96            // radius-candidate cap (mean ~31 for 512 slots)
#define NTILE 8             // 128 cols / 16
#define KSTEPS 30           // 960 / 32
#define WELEMS (NTILE * KSTEPS * 64 * 8)    // 122880 bf16 elements

typedef __attribute__((ext_vector_type(8))) short short8;
typedef __attribute__((ext_vector_type(4))) float f32x4;

__device__ __forceinline__ unsigned int f2bf(float f) {
    union { float f; unsigned int i; } v; v.f = f;
    return (v.i + 0x7fffu + ((v.i >> 16) & 1u)) >> 16;   // RNE
}
__device__ __forceinline__ float bflo(unsigned int u) {
    union { unsigned int i; float f; } v; v.i = u << 16; return v.f;
}
__device__ __forceinline__ float bfhi(unsigned int u) {
    union { unsigned int i; float f; } v; v.i = u & 0xFFFF0000u; return v.f;
}

// ---- prep: pack weights into MFMA B-fragment order (permuted K) + kpq/R2 ----
__global__ void wtrans_kernel(const float* __restrict__ w,
                              const float* __restrict__ kpts,
                              unsigned short* __restrict__ wTf,
                              float4* __restrict__ kpq_out) {  // [16]: 15 kpq + {R2}
    const int d = blockIdx.x * 256 + threadIdx.x;
    if (d < WELEMS) {
        const int j    = d & 7;
        const int lane = (d >> 3) & 63;
        const int ks   = (d >> 9) % KSTEPS;
        const int t    = d / (KSTEPS * 512);
        const int f    = ks * 32 + (lane >> 4) * 8 + j;
        const int cg   = f / 120;
        const int rem  = f - cg * 120;
        const int orig = (rem >> 3) * 64 + cg * 8 + (rem & 7);
        const int n    = t * 16 + (lane & 15);
        wTf[d] = (unsigned short)f2bf(w[(size_t)orig * COUT + n]);
    }
    if (blockIdx.x == 0 && threadIdx.x < 16) {
        const int k = threadIdx.x;
        if (k < KPn) {
            const float x = kpts[k * 3 + 0];
            const float y = kpts[k * 3 + 1];
            const float z = kpts[k * 3 + 2];
            kpq_out[k] = make_float4(x, y, z, x * x + y * y + z * z);
        } else {
            float mx = 0.f;
            for (int i = 0; i < KPn; ++i) {
                const float x = kpts[i * 3 + 0];
                const float y = kpts[i * 3 + 1];
                const float z = kpts[i * 3 + 2];
                mx = fmaxf(mx, x * x + y * y + z * z);
            }
            const float R = 0.1f + sqrtf(mx);
            kpq_out[15] = make_float4(R * R, 0.f, 0.f, 0.f);
        }
    }
}

__global__ __launch_bounds__(THREADS, 8) void kpconv_kernel(
    const float* __restrict__ pos,         // [N,3] f32
    const float* __restrict__ feats,       // [N,64] f32
    const unsigned short* __restrict__ wTf,// fragment-packed bf16 weights
    const float4* __restrict__ kpq_in,     // [16] precomputed kpq + R2
    const int*   __restrict__ neighbors,   // [N,32] int32
    float*       __restrict__ out)         // [N,128] f32
{
    __shared__ __align__(16) unsigned short wl[MPTS * WSTRIDE];   // 30976 B
    __shared__ __align__(16) unsigned short sfeat[RCAP * CIN];    // 12288 B bf16 staged feats
    __shared__ unsigned int  bpk[MPTS][BCAP];      // 3 KB: (e<<16)|(k<<12)|w12
    __shared__ int    bcnt[MPTS];
    __shared__ float  cposf[MPTS * 3];
    __shared__ float4 kpq[KPn];
    __shared__ float  rlx[RCAP], rly[RCAP], rlz[RCAP], rld[RCAP];
    __shared__ unsigned int rsl[RCAP];             // (p<<16) | nb
    __shared__ int    nact;

    const int tid = threadIdx.x;
    const int n0  = blockIdx.x * MPTS;

    // ---- hoisted gathers: issued BEFORE the init barrier so latency hides ----
    const int   p0  = tid >> 5;
    const int   nb0 = neighbors[(size_t)n0 * KNB + tid];
    const float qx  = pos[(size_t)nb0 * 3 + 0];
    const float qy  = pos[(size_t)nb0 * 3 + 1];
    const float qz  = pos[(size_t)nb0 * 3 + 2];
    const float R2  = kpq_in[15].x;                // uniform (scalar load)

    // ---- init ----
    if (tid < KPn) kpq[tid] = kpq_in[tid];
    if (tid < MPTS) bcnt[tid] = 0;
    if (tid == 0) nact = 0;
    if (tid < MPTS * 3) cposf[tid] = pos[(size_t)n0 * 3 + tid];
    __syncthreads();

    // ---- stage 1a-compact: radius filter, 1 slot per thread ----
    {
        const float rx = qx - cposf[p0 * 3 + 0];
        const float ry = qy - cposf[p0 * 3 + 1];
        const float rz = qz - cposf[p0 * 3 + 2];
        const float d2r = rx * rx + ry * ry + rz * rz;
        if (d2r < R2) {                           // ~6% survive
            const int idx = atomicAdd(&nact, 1);
            if (idx < RCAP) {
                rlx[idx] = rx; rly[idx] = ry; rlz[idx] = rz; rld[idx] = d2r;
                rsl[idx] = ((unsigned int)p0 << 16) | (unsigned int)nb0;
            }
        }
    }
    __syncthreads();

    // ---- stage 1a-k + feats staging (merged pass) ----
    // First E*16 items: cooperative gather of survivor feature rows -> LDS bf16
    //   (global loads issue in iteration 0 while kp-test VALU work proceeds).
    // Next E*16 items: exact kernel-point test, push (e,k,w12) into bucket.
    {
        const int E      = min(nact, RCAP);
        const int staged = E * 16;
        for (int u = tid; u < staged * 2; u += THREADS) {
            if (u < staged) {
                const int e = u >> 4;
                const int c = u & 15;
                const int nb = (int)(rsl[e] & 0xFFFFu);
                const float4 f = *(const float4*)(feats + (size_t)nb * CIN + c * 4);
                const unsigned int lo = f2bf(f.x) | (f2bf(f.y) << 16);
                const unsigned int hi = f2bf(f.z) | (f2bf(f.w) << 16);
                *(uint2*)(sfeat + e * CIN + c * 4) = make_uint2(lo, hi);
            } else {
                const int v = u - staged;
                const int e = v >> 4;
                const int k = v & 15;
                if (k < KPn) {
                    const float4 kp  = kpq[k];
                    const float  d2r = rld[e];
                    const float dot = rlx[e] * kp.x + rly[e] * kp.y + rlz[e] * kp.z;
                    if (dot > 0.5f * (d2r - 0.01f + kp.w)) {
                        const float d2 = fmaxf(d2r - 2.f * dot + kp.w, 0.f);
                        const float w  = 1.0f - 10.0f * sqrtf(d2);
                        const unsigned int wq = (unsigned int)(w * 4095.0f + 0.5f);
                        const int p = (int)(rsl[e] >> 16);
                        const int idx = atomicAdd(&bcnt[p], 1);
                        if (idx < BCAP)
                            bpk[p][idx] = ((unsigned int)e << 16) |
                                          ((unsigned int)k << 12) | wq;
                    }
                }
            }
        }
    }
    __syncthreads();

    // ---- stage 1b: ownership accumulation, LDS-only inner loop ----
    #pragma unroll
    for (int it = 0; it < 4; ++it) {
        const int wi = tid + it * THREADS;        // 0..2047
        const int cg = wi & 7;
        const int k  = (wi >> 3) & 15;
        const int p  = wi >> 7;                   // 0..15
        if (k < KPn) {
            float a0=0.f,a1=0.f,a2=0.f,a3=0.f,a4=0.f,a5=0.f,a6=0.f,a7=0.f;
            const int cnt = min(bcnt[p], BCAP);
            for (int e = 0; e < cnt; ++e) {
                const unsigned int id = bpk[p][e];
                if (((id >> 12) & 15u) == (unsigned int)k) {
                    const float wv = (float)(id & 4095u) * (1.0f / 4095.0f);
                    const uint4 vf = *(const uint4*)(sfeat + (id >> 16) * CIN + cg * 8);
                    a0 += wv * bflo(vf.x); a1 += wv * bfhi(vf.x);
                    a2 += wv * bflo(vf.y); a3 += wv * bfhi(vf.y);
                    a4 += wv * bflo(vf.z); a5 += wv * bfhi(vf.z);
                    a6 += wv * bflo(vf.w); a7 += wv * bfhi(vf.w);
                }
            }
            uint4 u;
            u.x = f2bf(a0) | (f2bf(a1) << 16);
            u.y = f2bf(a2) | (f2bf(a3) << 16);
            u.z = f2bf(a4) | (f2bf(a5) << 16);
            u.w = f2bf(a6) | (f2bf(a7) << 16);
            *(uint4*)(wl + p * WSTRIDE + cg * 120 + k * 8) = u;   // permuted-K
        }
    }
    __syncthreads();

    // ---- stage 2: out[16][128] = wl @ W; one N-tile per wave (8 waves) ----
    {
        const int wave = tid >> 6;                // 0..7 = N-tile
        const int lane = tid & 63;
        const int m    = lane & 15;
        const int q    = lane >> 4;

        f32x4 acc = {0.f, 0.f, 0.f, 0.f};
        const unsigned short* ap = wl + m * WSTRIDE + q * 8;
        const short8* bp = (const short8*)wTf + (size_t)wave * KSTEPS * 64 + lane;

        #pragma unroll 5
        for (int ks = 0; ks < KSTEPS; ++ks, ap += 32) {
            const short8 a = *(const short8*)ap;
            const short8 b = bp[ks * 64];
            acc = __builtin_amdgcn_mfma_f32_16x16x32_bf16(a, b, acc, 0, 0, 0);
        }

        // C/D layout: col = lane&15, row = q*4 + reg
        const int c = wave * 16 + m;
        #pragma unroll
        for (int r = 0; r < 4; ++r)
            out[(size_t)(n0 + q * 4 + r) * COUT + c] = acc[r];
    }
}

extern "C" void kernel_launch(void* const* d_in, const int* in_sizes, int n_in,
                              void* d_out, int out_size, void* d_ws, size_t ws_size,
                              hipStream_t stream) {
    const float* pos       = (const float*)d_in[0];
    const float* feats     = (const float*)d_in[1];
    const float* kpts      = (const float*)d_in[2];
    const float* weights   = (const float*)d_in[3];
    const int*   neighbors = (const int*)d_in[4];
    float*       out       = (float*)d_out;
    unsigned short* wTf    = (unsigned short*)d_ws;               // 245760 B
    float4* kpq            = (float4*)((char*)d_ws + WELEMS * 2); // 256 B

    wtrans_kernel<<<(WELEMS + 255) / 256, 256, 0, stream>>>(weights, kpts, wTf, kpq);
    kpconv_kernel<<<NPTS / MPTS, THREADS, 0, stream>>>(
        pos, feats, wTf, kpq, neighbors, out);
}

// Round 2
// 131.995 us; speedup vs baseline: 1.0522x; 1.0522x over previous
//
#include <hip/hip_runtime.h>

#define NPTS  65536
#define KNB   32
#define KPn   15
#define CIN   64
#define COUT  128
#define MPTS  16            // points per block (MFMA M)
#define THREADS 512         // 8 waves/block; target 4 blocks/CU = 32 waves/CU
#define WSTRIDE 968         // wl row stride in bf16 elems (960 + 8 pad)
#define BCAP  48            // bucket cap per point
#define RCAP  96            // radius-candidate cap (mean ~31 for 512 slots)
#define NTILE 8             // 128 cols / 16
#define KSTEPS 30           // 960 / 32
#define WELEMS (NTILE * KSTEPS * 64 * 8)    // 122880 bf16 elements

// shared-pool overlay offsets (bytes). All scratch is dead before wl is written,
// so everything lives inside wl's 30976-byte buffer.
#define POOL_BYTES (MPTS * WSTRIDE * 2)     // 30976
#define OFF_SFEAT  0                        // RCAP*CIN*2 = 12288
#define OFF_BPK    12288                    // MPTS*BCAP*4 = 3072
#define OFF_RLX    15360                    // RCAP*4 = 384
#define OFF_RLY    15744
#define OFF_RLZ    16128
#define OFF_RLD    16512
#define OFF_RSL    16896                    // end 17280 <= 30976

typedef __attribute__((ext_vector_type(8))) short short8;
typedef __attribute__((ext_vector_type(4))) float f32x4;

__device__ __forceinline__ unsigned int f2bf(float f) {
    union { float f; unsigned int i; } v; v.f = f;
    return (v.i + 0x7fffu + ((v.i >> 16) & 1u)) >> 16;   // RNE
}
__device__ __forceinline__ float bflo(unsigned int u) {
    union { unsigned int i; float f; } v; v.i = u << 16; return v.f;
}
__device__ __forceinline__ float bfhi(unsigned int u) {
    union { unsigned int i; float f; } v; v.i = u & 0xFFFF0000u; return v.f;
}

// ---- prep: pack weights into MFMA B-fragment order (permuted K) + kpq/R2 ----
__global__ void wtrans_kernel(const float* __restrict__ w,
                              const float* __restrict__ kpts,
                              unsigned short* __restrict__ wTf,
                              float4* __restrict__ kpq_out) {  // [16]: 15 kpq + {R2}
    const int d = blockIdx.x * 256 + threadIdx.x;
    if (d < WELEMS) {
        const int j    = d & 7;
        const int lane = (d >> 3) & 63;
        const int ks   = (d >> 9) % KSTEPS;
        const int t    = d / (KSTEPS * 512);
        const int f    = ks * 32 + (lane >> 4) * 8 + j;
        const int cg   = f / 120;
        const int rem  = f - cg * 120;
        const int orig = (rem >> 3) * 64 + cg * 8 + (rem & 7);
        const int n    = t * 16 + (lane & 15);
        wTf[d] = (unsigned short)f2bf(w[(size_t)orig * COUT + n]);
    }
    if (blockIdx.x == 0 && threadIdx.x < 16) {
        const int k = threadIdx.x;
        if (k < KPn) {
            const float x = kpts[k * 3 + 0];
            const float y = kpts[k * 3 + 1];
            const float z = kpts[k * 3 + 2];
            kpq_out[k] = make_float4(x, y, z, x * x + y * y + z * z);
        } else {
            float mx = 0.f;
            for (int i = 0; i < KPn; ++i) {
                const float x = kpts[i * 3 + 0];
                const float y = kpts[i * 3 + 1];
                const float z = kpts[i * 3 + 2];
                mx = fmaxf(mx, x * x + y * y + z * z);
            }
            const float R = 0.1f + sqrtf(mx);
            kpq_out[15] = make_float4(R * R, 0.f, 0.f, 0.f);
        }
    }
}

__global__ __launch_bounds__(THREADS, 8) void kpconv_kernel(
    const float* __restrict__ pos,         // [N,3] f32
    const float* __restrict__ feats,       // [N,64] f32
    const unsigned short* __restrict__ wTf,// fragment-packed bf16 weights
    const float4* __restrict__ kpq_in,     // [16] precomputed kpq + R2
    const int*   __restrict__ neighbors,   // [N,32] int32
    float*       __restrict__ out)         // [N,128] f32
{
    __shared__ __align__(16) unsigned char pool[POOL_BYTES];  // wl + overlaid scratch
    __shared__ int    bcnt[MPTS];
    __shared__ float  cposf[MPTS * 3];
    __shared__ float4 kpq[KPn];
    __shared__ int    nact;

    unsigned short* const wl    = (unsigned short*)pool;
    unsigned short* const sfeat = (unsigned short*)(pool + OFF_SFEAT);
    unsigned int*   const bpk   = (unsigned int*)(pool + OFF_BPK);   // [p*BCAP+i]
    float*          const rlx   = (float*)(pool + OFF_RLX);
    float*          const rly   = (float*)(pool + OFF_RLY);
    float*          const rlz   = (float*)(pool + OFF_RLZ);
    float*          const rld   = (float*)(pool + OFF_RLD);
    unsigned int*   const rsl   = (unsigned int*)(pool + OFF_RSL);   // (p<<16)|nb

    const int tid = threadIdx.x;
    const int n0  = blockIdx.x * MPTS;

    // ---- hoisted gathers: issued BEFORE the init barrier so latency hides ----
    const int   p0  = tid >> 5;
    const int   nb0 = neighbors[(size_t)n0 * KNB + tid];
    const float qx  = pos[(size_t)nb0 * 3 + 0];
    const float qy  = pos[(size_t)nb0 * 3 + 1];
    const float qz  = pos[(size_t)nb0 * 3 + 2];
    const float R2  = kpq_in[15].x;                // uniform

    // ---- init ----
    if (tid < KPn) kpq[tid] = kpq_in[tid];
    if (tid < MPTS) bcnt[tid] = 0;
    if (tid == 0) nact = 0;
    if (tid < MPTS * 3) cposf[tid] = pos[(size_t)n0 * 3 + tid];
    __syncthreads();

    // ---- stage 1a-compact: radius filter, 1 slot per thread ----
    {
        const float rx = qx - cposf[p0 * 3 + 0];
        const float ry = qy - cposf[p0 * 3 + 1];
        const float rz = qz - cposf[p0 * 3 + 2];
        const float d2r = rx * rx + ry * ry + rz * rz;
        if (d2r < R2) {                           // ~6% survive
            const int idx = atomicAdd(&nact, 1);
            if (idx < RCAP) {
                rlx[idx] = rx; rly[idx] = ry; rlz[idx] = rz; rld[idx] = d2r;
                rsl[idx] = ((unsigned int)p0 << 16) | (unsigned int)nb0;
            }
        }
    }
    __syncthreads();

    // ---- stage 1a-k + feats staging (merged pass) ----
    {
        const int E      = min(nact, RCAP);
        const int staged = E * 16;
        for (int u = tid; u < staged * 2; u += THREADS) {
            if (u < staged) {
                const int e = u >> 4;
                const int c = u & 15;
                const int nb = (int)(rsl[e] & 0xFFFFu);
                const float4 f = *(const float4*)(feats + (size_t)nb * CIN + c * 4);
                const unsigned int lo = f2bf(f.x) | (f2bf(f.y) << 16);
                const unsigned int hi = f2bf(f.z) | (f2bf(f.w) << 16);
                *(uint2*)(sfeat + e * CIN + c * 4) = make_uint2(lo, hi);
            } else {
                const int v = u - staged;
                const int e = v >> 4;
                const int k = v & 15;
                if (k < KPn) {
                    const float4 kp  = kpq[k];
                    const float  d2r = rld[e];
                    const float dot = rlx[e] * kp.x + rly[e] * kp.y + rlz[e] * kp.z;
                    if (dot > 0.5f * (d2r - 0.01f + kp.w)) {
                        const float d2 = fmaxf(d2r - 2.f * dot + kp.w, 0.f);
                        const float w  = 1.0f - 10.0f * sqrtf(d2);
                        const unsigned int wq = (unsigned int)(w * 4095.0f + 0.5f);
                        const int p = (int)(rsl[e] >> 16);
                        const int idx = atomicAdd(&bcnt[p], 1);
                        if (idx < BCAP)
                            bpk[p * BCAP + idx] = ((unsigned int)e << 16) |
                                                  ((unsigned int)k << 12) | wq;
                    }
                }
            }
        }
    }
    __syncthreads();

    // ---- stage 1b: accumulate in registers (LDS-only reads), THEN write wl.
    //      Scratch (sfeat/bpk/rl*) is dead after the accumulate phase, so wl
    //      overlays it: all results are held in regs across the barrier. ----
    uint4 res[4];
    #pragma unroll
    for (int it = 0; it < 4; ++it) {
        const int wi = tid + it * THREADS;        // 0..2047
        const int cg = wi & 7;
        const int k  = (wi >> 3) & 15;
        const int p  = wi >> 7;                   // 0..15
        uint4 u = make_uint4(0u, 0u, 0u, 0u);
        if (k < KPn) {
            float a0=0.f,a1=0.f,a2=0.f,a3=0.f,a4=0.f,a5=0.f,a6=0.f,a7=0.f;
            const int cnt = min(bcnt[p], BCAP);
            for (int e = 0; e < cnt; ++e) {
                const unsigned int id = bpk[p * BCAP + e];
                if (((id >> 12) & 15u) == (unsigned int)k) {
                    const float wv = (float)(id & 4095u) * (1.0f / 4095.0f);
                    const uint4 vf = *(const uint4*)(sfeat + (id >> 16) * CIN + cg * 8);
                    a0 += wv * bflo(vf.x); a1 += wv * bfhi(vf.x);
                    a2 += wv * bflo(vf.y); a3 += wv * bfhi(vf.y);
                    a4 += wv * bflo(vf.z); a5 += wv * bfhi(vf.z);
                    a6 += wv * bflo(vf.w); a7 += wv * bfhi(vf.w);
                }
            }
            u.x = f2bf(a0) | (f2bf(a1) << 16);
            u.y = f2bf(a2) | (f2bf(a3) << 16);
            u.z = f2bf(a4) | (f2bf(a5) << 16);
            u.w = f2bf(a6) | (f2bf(a7) << 16);
        }
        res[it] = u;
    }
    __syncthreads();                              // scratch reads done -> reuse as wl
    #pragma unroll
    for (int it = 0; it < 4; ++it) {
        const int wi = tid + it * THREADS;
        const int cg = wi & 7;
        const int k  = (wi >> 3) & 15;
        const int p  = wi >> 7;
        if (k < KPn)
            *(uint4*)(wl + p * WSTRIDE + cg * 120 + k * 8) = res[it];  // permuted-K
    }
    __syncthreads();

    // ---- stage 2: out[16][128] = wl @ W; one N-tile per wave (8 waves) ----
    {
        const int wave = tid >> 6;                // 0..7 = N-tile
        const int lane = tid & 63;
        const int m    = lane & 15;
        const int q    = lane >> 4;

        f32x4 acc = {0.f, 0.f, 0.f, 0.f};
        const unsigned short* ap = wl + m * WSTRIDE + q * 8;
        const short8* bp = (const short8*)wTf + (size_t)wave * KSTEPS * 64 + lane;

        #pragma unroll 5
        for (int ks = 0; ks < KSTEPS; ++ks, ap += 32) {
            const short8 a = *(const short8*)ap;
            const short8 b = bp[ks * 64];
            acc = __builtin_amdgcn_mfma_f32_16x16x32_bf16(a, b, acc, 0, 0, 0);
        }

        // C/D layout: col = lane&15, row = q*4 + reg
        const int c = wave * 16 + m;
        #pragma unroll
        for (int r = 0; r < 4; ++r)
            out[(size_t)(n0 + q * 4 + r) * COUT + c] = acc[r];
    }
}

extern "C" void kernel_launch(void* const* d_in, const int* in_sizes, int n_in,
                              void* d_out, int out_size, void* d_ws, size_t ws_size,
                              hipStream_t stream) {
    const float* pos       = (const float*)d_in[0];
    const float* feats     = (const float*)d_in[1];
    const float* kpts      = (const float*)d_in[2];
    const float* weights   = (const float*)d_in[3];
    const int*   neighbors = (const int*)d_in[4];
    float*       out       = (float*)d_out;
    unsigned short* wTf    = (unsigned short*)d_ws;               // 245760 B
    float4* kpq            = (float4*)((char*)d_ws + WELEMS * 2); // 256 B

    wtrans_kernel<<<(WELEMS + 255) / 256, 256, 0, stream>>>(weights, kpts, wTf, kpq);
    kpconv_kernel<<<NPTS / MPTS, THREADS, 0, stream>>>(
        pos, feats, wTf, kpq, neighbors, out);
}